// Round 7
// baseline (479.510 us; speedup 1.0000x reference)
//
#include <hip/hip_runtime.h>

#define NN   46
#define FIN  1024
#define NNF  (NN * FIN)
#define C1   256
#define C2   64

typedef __attribute__((ext_vector_type(4))) float f32x4;
typedef __attribute__((ext_vector_type(16))) float f32x16;
typedef __attribute__((ext_vector_type(8))) short bf16x8;

// ---------------- LDS layout (byte offsets, phase-aliased) ----------------
// P1:   Abuf0 [46][264] bf16 @0       (24,288)  quarter-K x tile (q even)
//       Abuf1            @24,288      (24,288)  (q odd)
//       B     [256][64]  @48,576      (32,768)  one 64-K B tile per kt, XOR-chunk swizzle
// tail (aliases A region only; B region untouched by tail):
//       g1T [8][32][56] bf16 @0 (28,672); SS @28,672 SD @30,208 SI @31,808 (f32[8][48])
//       H1 [48][264] bf16 @0 (25,344); G2 [46][69] f32 @25,600 (ends 38,296)
//       S2S @38,400 S2D @38,656 GM @38,912 PL @39,168 Z1 @39,424
#define AB0_OFF 0
#define AB1_OFF 24288
#define B_OFF   48576
#define G1T_OFF 0
#define SS_OFF  28672
#define SD_OFF  30208
#define SI_OFF  31808
#define H1_OFF  0
#define G2_OFF  25600
#define S2S_OFF 38400
#define S2D_OFF 38656
#define GM_OFF  38912
#define PL_OFF  39168
#define Z1_OFF  39424
#define SMEM_SZ 81344

__device__ __forceinline__ float bf2f(unsigned short u) {
  union { unsigned int i; float f; } v; v.i = ((unsigned int)u) << 16; return v.f;
}
__device__ __forceinline__ unsigned short f2bf(float f) {
  unsigned int u = __float_as_uint(f);
  u += 0x7fffu + ((u >> 16) & 1u);
  return (unsigned short)(u >> 16);
}
__device__ __forceinline__ float lrelu(float x) { return x > 0.f ? x : 0.2f * x; }

__device__ __forceinline__ void glds16(const void* g, void* l) {
  __builtin_amdgcn_global_load_lds(
      (const __attribute__((address_space(1))) unsigned int*)g,
      (__attribute__((address_space(3))) unsigned int*)l, 16, 0, 0);
}

// x quarter load (46 rows x 256 f32 = 2944 float4, 6 iters x 512 thr) from base p_
#define XLOADP(p_, q) do { _Pragma("unroll") \
  for (int i_ = 0; i_ < 6; ++i_) { int idx_ = tid + i_ * 512; \
    if (idx_ < 2944) { int r_ = idx_ >> 6, c_ = idx_ & 63; \
      xv[i_] = *(const float4*)((p_) + r_ * FIN + (q) * 256 + c_ * 4); } } } while (0)

#define XWRITE(b) do { unsigned short* Ap_ = (unsigned short*)(smem + ((b) ? AB1_OFF : AB0_OFF)); \
  _Pragma("unroll") \
  for (int i_ = 0; i_ < 6; ++i_) { int idx_ = tid + i_ * 512; \
    if (idx_ < 2944) { int r_ = idx_ >> 6, c_ = idx_ & 63; \
      ushort4 u_; u_.x = f2bf(xv[i_].x); u_.y = f2bf(xv[i_].y); \
      u_.z = f2bf(xv[i_].z); u_.w = f2bf(xv[i_].w); \
      *(ushort4*)(Ap_ + r_ * 264 + c_ * 4) = u_; } } } while (0)

__global__ __launch_bounds__(512, 4) void gat_main(
    const float* __restrict__ x,
    const float* __restrict__ a1, const float* __restrict__ a2,
    const float* __restrict__ Wm1, const float* __restrict__ bm1,
    const float* __restrict__ Wm2, const float* __restrict__ bm2,
    const unsigned short* __restrict__ W1T, const unsigned short* __restrict__ W2T,
    float* __restrict__ out, int total, int spb)
{
  __shared__ __attribute__((aligned(128))) unsigned char smem[SMEM_SZ];

  const int tid  = threadIdx.x;
  const int wave = tid >> 6;
  const int lane = tid & 63;
  const int l16  = lane & 15;
  const int q4   = lane >> 4;
  const int kq8  = q4 * 8;
  const int rq4  = q4 * 4;
  const int l32  = lane & 31;
  const int hh   = lane >> 5;

  const int gs0 = blockIdx.x * spb;
  float4 xv[6];

  // prologue: prefetch first sample's q0 into registers
  if (gs0 < total) XLOADP(x + (size_t)gs0 * NNF, 0);

  for (int s = 0; s < spb; ++s) {
    const int gs = gs0 + s;
    if (gs >= total) break;
    const float* __restrict__ xb = x + (size_t)gs * NNF;
    const int gsn = (gs + 1 < total) ? gs + 1 : gs;
    const float* __restrict__ xbn = x + (size_t)gsn * NNF;

    // ===== Phase 1: g1 = bf16(x) @ bf16(W1)  (46x256, K=1024) — r3 structure =====
    XWRITE(0);                       // xv holds q0 (prologue / prev tail prefetch)
    XLOADP(xb, 1);

    f32x4 acc[3][2];
#pragma unroll
    for (int i = 0; i < 3; ++i) { acc[i][0] = 0; acc[i][1] = 0; }

    for (int kt = 0; kt < 16; ++kt) {
      // issue B[kt] via global_load_lds (linear dest, inverse-swizzled source)
#pragma unroll
      for (int i = 0; i < 4; ++i) {
        int rr = wave * 32 + i * 8 + (lane >> 3);
        int j  = lane & 7;
        const unsigned short* src = W1T + (size_t)rr * FIN + kt * 64 + ((j ^ (rr & 7)) << 3);
        glds16(src, smem + B_OFF + (wave * 32 + i * 8) * 128);
      }
      __syncthreads();               // B(kt) landed; XWRITE(0) lgkm drained (kt=0)

      if ((kt & 3) == 0 && kt < 12) {
        int qw = (kt >> 2) + 1;
        XWRITE(qw & 1);              // target buf's old content last read >=1 quarter ago
        if (qw < 3) XLOADP(xb, qw + 1);
      }

      const unsigned short* Ap = (const unsigned short*)(smem + (((kt >> 2) & 1) ? AB1_OFF : AB0_OFF));
      const int ktl = kt & 3;
#pragma unroll
      for (int ks = 0; ks < 2; ++ks) {
        bf16x8 af[3], bfr[2];
#pragma unroll
        for (int rt = 0; rt < 3; ++rt)
          af[rt] = *(const bf16x8*)(Ap + (rt * 16 + l16) * 264 + ktl * 64 + ks * 32 + kq8);
#pragma unroll
        for (int ct = 0; ct < 2; ++ct) {
          int brow  = wave * 32 + ct * 16 + l16;
          int chunk = (ks * 4 + q4) ^ (l16 & 7);
          bfr[ct] = *(const bf16x8*)(smem + B_OFF + brow * 128 + chunk * 16);
        }
#pragma unroll
        for (int rt = 0; rt < 3; ++rt)
#pragma unroll
          for (int ct = 0; ct < 2; ++ct)
            acc[rt][ct] = __builtin_amdgcn_mfma_f32_16x16x32_bf16(af[rt], bfr[ct], acc[rt][ct], 0, 0, 0);
      }
      __syncthreads();               // all waves done reading B(kt) before next glds
    }

    // ===== GEMM1 epilogue: acc -> g1T[head][d][j] + SS/SD via shfl =====
    {
      unsigned short* g1T = (unsigned short*)(smem + G1T_OFF);
      float* SSp = (float*)(smem + SS_OFF);
      float* SDp = (float*)(smem + SD_OFF);
      float a1s[2], a1d[2];
#pragma unroll
      for (int ct = 0; ct < 2; ++ct) {
        a1s[ct] = a1[ct * 16 + l16];
        a1d[ct] = a1[32 + ct * 16 + l16];
      }
#pragma unroll
      for (int rt = 0; rt < 3; ++rt)
#pragma unroll
        for (int r = 0; r < 4; ++r) {
          int row = rt * 16 + rq4 + r;   // C row = (lane>>4)*4 + reg
          float ss = acc[rt][0][r] * a1s[0] + acc[rt][1][r] * a1s[1];
          float sd = acc[rt][0][r] * a1d[0] + acc[rt][1][r] * a1d[1];
#pragma unroll
          for (int m = 1; m < 16; m <<= 1) {
            ss += __shfl_xor(ss, m);
            sd += __shfl_xor(sd, m);
          }
          const bool ok = row < NN;
          // rows 46/47 write 0: PV K-pad must see FINITE zeros (NaN bug, r4)
#pragma unroll
          for (int ct = 0; ct < 2; ++ct)
            g1T[wave * 1792 + (ct * 16 + l16) * 56 + row] =
                ok ? f2bf(acc[rt][ct][r]) : (unsigned short)0;
          if (ok && l16 == 0) { SSp[wave * 48 + row] = ss; SDp[wave * 48 + row] = sd; }
        }
    }
    __syncthreads();

    // ===== PV: in-register P build (wave = head) + MFMA 32x32x16 =====
    f32x16 pv0 = 0, pv1 = 0;
    {
      const float* SSp = (const float*)(smem + SS_OFF);
      const float* SDp = (const float*)(smem + SD_OFF);
      float* SIp = (float*)(smem + SI_OFF);

      float sdl = (lane < NN) ? SDp[wave * 48 + lane] : -1e30f;
#pragma unroll
      for (int m = 1; m < 64; m <<= 1) sdl = fmaxf(sdl, __shfl_xor(sdl, m));
      const float sdmax = sdl;       // exact row max: lrelu monotone

      const int row0 = l32, row1 = 32 + l32;
      const bool r1ok = row1 < NN;
      const float ss0 = SSp[wave * 48 + row0];
      const float ss1 = r1ok ? SSp[wave * 48 + row1] : 0.f;
      const float m0 = lrelu(ss0 + sdmax);
      const float m1 = lrelu(ss1 + sdmax);

      bf16x8 pa0[3], pa1[3];
      float sum0 = 0.f, sum1 = 0.f;
#pragma unroll
      for (int ks = 0; ks < 3; ++ks) {
        const int jbase = ks * 16 + hh * 8;
        const float* sdp = SDp + wave * 48 + jbase;
        const float4 sa = *(const float4*)(sdp);
        const float4 sb = *(const float4*)(sdp + 4);
        float sj[8] = { sa.x, sa.y, sa.z, sa.w, sb.x, sb.y, sb.z, sb.w };
#pragma unroll
        for (int jj = 0; jj < 8; ++jj) {
          float p0 = 0.f, p1 = 0.f;
          if (jbase + jj < NN) {
            p0 = __expf(lrelu(ss0 + sj[jj]) - m0); sum0 += p0;
            if (r1ok) { p1 = __expf(lrelu(ss1 + sj[jj]) - m1); sum1 += p1; }
          }
          ((unsigned short*)&pa0[ks])[jj] = f2bf(p0);
          ((unsigned short*)&pa1[ks])[jj] = f2bf(p1);
        }
      }
      sum0 += __shfl_xor(sum0, 32);
      sum1 += __shfl_xor(sum1, 32);
      if (hh == 0) {
        SIp[wave * 48 + row0] = 1.f / sum0;
        if (r1ok) SIp[wave * 48 + row1] = 1.f / sum1;
      }

      const unsigned short* Gt = (const unsigned short*)(smem + G1T_OFF);
#pragma unroll
      for (int ks = 0; ks < 3; ++ks) {
        bf16x8 bfrag = *(const bf16x8*)(Gt + wave * 1792 + l32 * 56 + ks * 16 + hh * 8);
        pv0 = __builtin_amdgcn_mfma_f32_32x32x16_bf16(pa0[ks], bfrag, pv0, 0, 0, 0);
        pv1 = __builtin_amdgcn_mfma_f32_32x32x16_bf16(pa1[ks], bfrag, pv1, 0, 0, 0);
      }
    }
    __syncthreads();   // g1T reads done before H1 aliases

    // prefetch next sample's q0 into registers (hides under the whole tail)
    XLOADP(xbn, 0);

    // ===== PV epilogue: scale by 1/sum, ELU, -> H1[48][264] bf16; zero pad rows =====
    {
      unsigned short* H1p = (unsigned short*)(smem + H1_OFF);
      const float* SIp = (const float*)(smem + SI_OFF);
#pragma unroll
      for (int mt = 0; mt < 2; ++mt)
#pragma unroll
        for (int rg = 0; rg < 16; ++rg) {
          int row = mt * 32 + (rg & 3) + 8 * (rg >> 2) + 4 * hh;  // 32x32 C layout
          if (row < NN) {
            float v = (mt ? pv1[rg] : pv0[rg]) * SIp[wave * 48 + row];
            v = v > 0.f ? v : __expf(v) - 1.f;   // ELU
            H1p[row * 264 + wave * 32 + l32] = f2bf(v);
          }
        }
      if (tid < 132) *(unsigned long long*)((char*)H1p + 46 * 528 + tid * 8) = 0ull;
    }
    __syncthreads();

    // ===== Phase 4: g2 = h1 @ W2 (46x64, K=256), B frags from L2-resident W2T =====
    {
      const unsigned short* H1p = (const unsigned short*)(smem + H1_OFF);
      float* G2p = (float*)(smem + G2_OFF);
      for (int tile = wave; tile < 12; tile += 8) {
        int rt = tile >> 2, ct = tile & 3;
        f32x4 a4 = 0;
#pragma unroll
        for (int ks = 0; ks < 8; ++ks) {
          bf16x8 af = *(const bf16x8*)(H1p + (rt * 16 + l16) * 264 + ks * 32 + kq8);
          bf16x8 bw = *(const bf16x8*)(W2T + (ct * 16 + l16) * 256 + ks * 32 + kq8);
          a4 = __builtin_amdgcn_mfma_f32_16x16x32_bf16(af, bw, a4, 0, 0, 0);
        }
#pragma unroll
        for (int r = 0; r < 4; ++r) {
          int row = rt * 16 + rq4 + r;
          if (row < NN) G2p[row * 69 + ct * 16 + l16] = a4[r];
        }
      }
    }
    __syncthreads();

    // ===== Phase 5: s2_src/s2_dst/gmean per node (368 lanes, 8-lane reduce) =====
    {
      const float* G2p = (const float*)(smem + G2_OFF);
      float* S2S = (float*)(smem + S2S_OFF);
      float* S2D = (float*)(smem + S2D_OFF);
      float* GM  = (float*)(smem + GM_OFF);
      if (tid < NN * 8) {
        int n = tid >> 3, dp = (tid & 7) * 8;
        const float* g = G2p + n * 69 + dp;
        float ss = 0.f, sd = 0.f, gm = 0.f;
#pragma unroll
        for (int d = 0; d < 8; ++d) {
          float gv = g[d];
          ss += gv * a2[dp + d]; sd += gv * a2[64 + dp + d]; gm += gv;
        }
#pragma unroll
        for (int m = 1; m < 8; m <<= 1) {
          ss += __shfl_xor(ss, m); sd += __shfl_xor(sd, m); gm += __shfl_xor(gm, m);
        }
        if ((tid & 7) == 0) { S2S[n] = ss; S2D[n] = sd; GM[n] = gm * (1.f / 64.f); }
      }
    }
    __syncthreads();

    // ===== Phase 6: attn2 softmax + pooled[i] = sum_j p_ij * gmean[j] =====
    {
      const float* S2S = (const float*)(smem + S2S_OFF);
      const float* S2D = (const float*)(smem + S2D_OFF);
      const float* GM  = (const float*)(smem + GM_OFF);
      float* PL = (float*)(smem + PL_OFF);
      if (tid < NN) {
        float si = S2S[tid];
        float m = -1e30f;
        for (int j = 0; j < NN; ++j) m = fmaxf(m, lrelu(si + S2D[j]));
        float sum = 0.f, accp = 0.f;
        for (int j = 0; j < NN; ++j) {
          float p = __expf(lrelu(si + S2D[j]) - m);
          sum += p; accp += p * GM[j];
        }
        PL[tid] = accp / sum;
      }
    }
    __syncthreads();

    // ===== Phase 7: MLP head + sigmoid =====
    {
      const float* PL = (const float*)(smem + PL_OFF);
      float* Z1 = (float*)(smem + Z1_OFF);
      if (tid < 12) {
        float z = 0.f;
        for (int i = 0; i < NN; ++i) z += PL[i] * Wm1[i * 12 + tid];
        Z1[tid] = z + bm1[tid];
      }
      __syncthreads();
      if (tid == 0) {
        float z = 0.f;
#pragma unroll
        for (int mm = 0; mm < 12; ++mm) z += Z1[mm] * Wm2[mm];
        z += bm2[0];
        out[gs] = 1.f / (1.f + __expf(-z));
      }
    }
    __syncthreads();   // conservative sample boundary: all tail reads done
  }
}

// Transpose + bf16-cast weights once per launch into workspace.
__global__ void gat_prep(const float* __restrict__ W1, const float* __restrict__ W2,
                         unsigned short* __restrict__ W1T, unsigned short* __restrict__ W2T)
{
  int id = blockIdx.x * 256 + threadIdx.x;
  if (id < FIN * C1) {                 // W1 [1024][256] -> W1T [256][1024]
    int k = id >> 8, n = id & 255;
    W1T[n * FIN + k] = f2bf(W1[id]);
  }
  if (id < C1 * C2) {                  // W2 [256][64] -> W2T [64][256]
    int k = id >> 6, n = id & 63;
    W2T[n * C1 + k] = f2bf(W2[id]);
  }
}

extern "C" void kernel_launch(void* const* d_in, const int* in_sizes, int n_in,
                              void* d_out, int out_size, void* d_ws, size_t ws_size,
                              hipStream_t stream)
{
  const float* x   = (const float*)d_in[0];
  // d_in[1] = adj_mat (all ones by construction) — attention is dense, ignored
  const float* W1  = (const float*)d_in[2];
  const float* a1  = (const float*)d_in[3];
  const float* W2  = (const float*)d_in[4];
  const float* a2  = (const float*)d_in[5];
  const float* Wm1 = (const float*)d_in[6];
  const float* bm1 = (const float*)d_in[7];
  const float* Wm2 = (const float*)d_in[8];
  const float* bm2 = (const float*)d_in[9];
  float* out = (float*)d_out;

  unsigned short* W1T = (unsigned short*)d_ws;
  unsigned short* W2T = (unsigned short*)((char*)d_ws + (size_t)FIN * C1 * 2);

  int total = in_sizes[0] / NNF;
  int grid  = total < 512 ? total : 512;
  int spb   = (total + grid - 1) / grid;

  hipLaunchKernelGGL(gat_prep, dim3(1024), dim3(256), 0, stream, W1, W2, W1T, W2T);
  hipLaunchKernelGGL(gat_main, dim3(grid), dim3(512), 0, stream,
                     x, a1, a2, Wm1, bm1, Wm2, bm2, W1T, W2T, out, total, spb);
}

// Round 8
// 358.932 us; speedup vs baseline: 1.3359x; 1.3359x over previous
//
#include <hip/hip_runtime.h>

#define NN   46
#define FIN  1024
#define NNF  (NN * FIN)
#define C1   256
#define C2   64

typedef __attribute__((ext_vector_type(4))) float f32x4;
typedef __attribute__((ext_vector_type(16))) float f32x16;
typedef __attribute__((ext_vector_type(8))) short bf16x8;

// ---------------- LDS layout (byte offsets, phase-aliased) ----------------
// P1:   Abuf0 [46][264] bf16 @0       (24,288)  quarter-K x tile (q even)
//       Abuf1            @24,288      (24,288)  (q odd)
//       Bbuf0 [256][64B] @48,576      (16,384)  K=32 B chunk (kt even), row-XOR swizzle
//       Bbuf1            @64,960      (16,384)  (kt odd)  -> 81,344
// tail (aliases A region only; B region untouched by tail):
//       g1T [8][32][56] bf16 @0 (28,672); SS @28,672 SD @30,208 SI @31,808 (f32[8][48])
//       H1 [48][264] bf16 @0 (25,344); G2 [46][69] f32 @25,600 (ends 38,296)
//       S2S @38,400 S2D @38,656 GM @38,912 PL @39,168 Z1 @39,424
#define AB0_OFF 0
#define AB1_OFF 24288
#define BB0_OFF 48576
#define BB1_OFF 64960
#define G1T_OFF 0
#define SS_OFF  28672
#define SD_OFF  30208
#define SI_OFF  31808
#define H1_OFF  0
#define G2_OFF  25600
#define S2S_OFF 38400
#define S2D_OFF 38656
#define GM_OFF  38912
#define PL_OFF  39168
#define Z1_OFF  39424
#define SMEM_SZ 81344

__device__ __forceinline__ float bf2f(unsigned short u) {
  union { unsigned int i; float f; } v; v.i = ((unsigned int)u) << 16; return v.f;
}
__device__ __forceinline__ unsigned short f2bf(float f) {
  unsigned int u = __float_as_uint(f);
  u += 0x7fffu + ((u >> 16) & 1u);
  return (unsigned short)(u >> 16);
}
__device__ __forceinline__ float lrelu(float x) { return x > 0.f ? x : 0.2f * x; }

__device__ __forceinline__ void glds16(const void* g, void* l) {
  __builtin_amdgcn_global_load_lds(
      (const __attribute__((address_space(1))) unsigned int*)g,
      (__attribute__((address_space(3))) unsigned int*)l, 16, 0, 0);
}

// one x slice (512 float4) of quarter q_ into xv[j_]
#define XSLICE(p_, q_, j_) do { int idx_ = tid + (j_) * 512; \
  if (idx_ < 2944) { int r_ = idx_ >> 6, c_ = idx_ & 63; \
    xv[j_] = *(const float4*)((p_) + r_ * FIN + (q_) * 256 + c_ * 4); } } while (0)

#define XLOADP(p_, q_) do { _Pragma("unroll") \
  for (int j_ = 0; j_ < 6; ++j_) XSLICE(p_, q_, j_); } while (0)

#define XWRITE(b) do { unsigned short* Ap_ = (unsigned short*)(smem + ((b) ? AB1_OFF : AB0_OFF)); \
  _Pragma("unroll") \
  for (int i_ = 0; i_ < 6; ++i_) { int idx_ = tid + i_ * 512; \
    if (idx_ < 2944) { int r_ = idx_ >> 6, c_ = idx_ & 63; \
      ushort4 u_; u_.x = f2bf(xv[i_].x); u_.y = f2bf(xv[i_].y); \
      u_.z = f2bf(xv[i_].z); u_.w = f2bf(xv[i_].w); \
      *(ushort4*)(Ap_ + r_ * 264 + c_ * 4) = u_; } } } while (0)

// issue glds for B chunk kt_ (K=32 = 64B/row, 256 rows = 16 KB) into Bbuf[kt_&1].
// store-side swizzle: stored chunk c=lane&3 of row r holds src element-chunk
// e = c ^ (r&3) ^ ((r>>2)&3); read side inverts (conflict-free ds_read_b128).
#define GLDSB(kt_) do { \
  unsigned char* bb_ = smem + (((kt_) & 1) ? BB1_OFF : BB0_OFF); \
  const int e_ = (lane & 3) ^ ((lane >> 2) & 3) ^ (lane >> 4); \
  _Pragma("unroll") \
  for (int i_ = 0; i_ < 2; ++i_) { \
    int row_ = wave * 32 + i_ * 16 + (lane >> 2); \
    const unsigned short* src_ = W1T + (size_t)row_ * FIN + (kt_) * 32 + e_ * 8; \
    glds16(src_, bb_ + (wave * 32 + i_ * 16) * 64); } } while (0)

__global__ __launch_bounds__(512, 4) void gat_main(
    const float* __restrict__ x,
    const float* __restrict__ a1, const float* __restrict__ a2,
    const float* __restrict__ Wm1, const float* __restrict__ bm1,
    const float* __restrict__ Wm2, const float* __restrict__ bm2,
    const unsigned short* __restrict__ W1T, const unsigned short* __restrict__ W2T,
    float* __restrict__ out)
{
  __shared__ __attribute__((aligned(128))) unsigned char smem[SMEM_SZ];

  const int tid  = threadIdx.x;
  const int wave = tid >> 6;
  const int lane = tid & 63;
  const int l16  = lane & 15;
  const int q4   = lane >> 4;
  const int kq8  = q4 * 8;
  const int rq4  = q4 * 4;
  const int l32  = lane & 31;
  const int hh   = lane >> 5;
  const int bchunk = q4 ^ (l16 & 3) ^ (l16 >> 2);   // B read chunk (see GLDSB)
  const float* __restrict__ xb = x + (size_t)blockIdx.x * NNF;

  float4 xv[6];

  // ===== Phase 1: g1 = bf16(x) @ bf16(W1)  (46x256, K=1024) =====
  // A: quarter-K bf16 dbuf; B: K=32 glds dbuf, ONE sync per kt -> glds(kt+1)
  // spans compute(kt); x slices issued 1/kt to keep HBM queue continuously full.
  XLOADP(xb, 0);
  XWRITE(0);
  GLDSB(0);
  __syncthreads();               // Abuf0 + Bbuf0 visible

  f32x4 acc[3][2];
#pragma unroll
  for (int i = 0; i < 3; ++i) { acc[i][0] = 0; acc[i][1] = 0; }

  for (int q = 0; q < 4; ++q) {
    const unsigned short* Ap = (const unsigned short*)(smem + ((q & 1) ? AB1_OFF : AB0_OFF));
#pragma unroll
    for (int ktl = 0; ktl < 8; ++ktl) {
      const int kt = q * 8 + ktl;
      if (kt) __syncthreads();   // B(kt) landed; Bbuf[(kt+1)&1] old reads done pre-sync
      if (kt < 31) GLDSB(kt + 1);
      if (q < 3) {
        if (ktl < 6) XSLICE(xb, q + 1, ktl);       // spread issue: 1 slice/kt
        else if (ktl == 7) XWRITE((q + 1) & 1);    // target's old content dead 8 syncs ago
      }
      // compute kt: K=32, 6 MFMAs
      bf16x8 af[3], bfr[2];
#pragma unroll
      for (int rt = 0; rt < 3; ++rt)
        af[rt] = *(const bf16x8*)(Ap + (rt * 16 + l16) * 264 + ktl * 32 + kq8);
      const unsigned char* Bp = smem + ((kt & 1) ? BB1_OFF : BB0_OFF);
#pragma unroll
      for (int ct = 0; ct < 2; ++ct) {
        int brow = wave * 32 + ct * 16 + l16;
        bfr[ct] = *(const bf16x8*)(Bp + brow * 64 + bchunk * 16);
      }
#pragma unroll
      for (int rt = 0; rt < 3; ++rt)
#pragma unroll
        for (int ct = 0; ct < 2; ++ct)
          acc[rt][ct] = __builtin_amdgcn_mfma_f32_16x16x32_bf16(af[rt], bfr[ct], acc[rt][ct], 0, 0, 0);
    }
  }
  __syncthreads();               // A region dead; g1T/SS/SD alias it

  // ===== GEMM1 epilogue: acc -> g1T[head][d][j] + SS/SD via shfl =====
  {
    unsigned short* g1T = (unsigned short*)(smem + G1T_OFF);
    float* SSp = (float*)(smem + SS_OFF);
    float* SDp = (float*)(smem + SD_OFF);
    float a1s[2], a1d[2];
#pragma unroll
    for (int ct = 0; ct < 2; ++ct) {
      a1s[ct] = a1[ct * 16 + l16];
      a1d[ct] = a1[32 + ct * 16 + l16];
    }
#pragma unroll
    for (int rt = 0; rt < 3; ++rt)
#pragma unroll
      for (int r = 0; r < 4; ++r) {
        int row = rt * 16 + rq4 + r;   // C row = (lane>>4)*4 + reg
        float ss = acc[rt][0][r] * a1s[0] + acc[rt][1][r] * a1s[1];
        float sd = acc[rt][0][r] * a1d[0] + acc[rt][1][r] * a1d[1];
#pragma unroll
        for (int m = 1; m < 16; m <<= 1) {
          ss += __shfl_xor(ss, m);
          sd += __shfl_xor(sd, m);
        }
        const bool ok = row < NN;
        // rows 46/47 write 0: PV K-pad must see FINITE zeros (NaN bug, r4)
#pragma unroll
        for (int ct = 0; ct < 2; ++ct)
          g1T[wave * 1792 + (ct * 16 + l16) * 56 + row] =
              ok ? f2bf(acc[rt][ct][r]) : (unsigned short)0;
        if (ok && l16 == 0) { SSp[wave * 48 + row] = ss; SDp[wave * 48 + row] = sd; }
      }
  }
  __syncthreads();

  // ===== PV: in-register P build (wave = head) + MFMA 32x32x16 =====
  f32x16 pv0 = 0, pv1 = 0;
  {
    const float* SSp = (const float*)(smem + SS_OFF);
    const float* SDp = (const float*)(smem + SD_OFF);
    float* SIp = (float*)(smem + SI_OFF);

    float sdl = (lane < NN) ? SDp[wave * 48 + lane] : -1e30f;
#pragma unroll
    for (int m = 1; m < 64; m <<= 1) sdl = fmaxf(sdl, __shfl_xor(sdl, m));
    const float sdmax = sdl;       // exact row max: lrelu monotone

    const int row0 = l32, row1 = 32 + l32;
    const bool r1ok = row1 < NN;
    const float ss0 = SSp[wave * 48 + row0];
    const float ss1 = r1ok ? SSp[wave * 48 + row1] : 0.f;
    const float m0 = lrelu(ss0 + sdmax);
    const float m1 = lrelu(ss1 + sdmax);

    bf16x8 pa0[3], pa1[3];
    float sum0 = 0.f, sum1 = 0.f;
#pragma unroll
    for (int ks = 0; ks < 3; ++ks) {
      const int jbase = ks * 16 + hh * 8;
      const float* sdp = SDp + wave * 48 + jbase;
      const float4 sa = *(const float4*)(sdp);
      const float4 sb = *(const float4*)(sdp + 4);
      float sj[8] = { sa.x, sa.y, sa.z, sa.w, sb.x, sb.y, sb.z, sb.w };
#pragma unroll
      for (int jj = 0; jj < 8; ++jj) {
        float p0 = 0.f, p1 = 0.f;
        if (jbase + jj < NN) {
          p0 = __expf(lrelu(ss0 + sj[jj]) - m0); sum0 += p0;
          if (r1ok) { p1 = __expf(lrelu(ss1 + sj[jj]) - m1); sum1 += p1; }
        }
        ((unsigned short*)&pa0[ks])[jj] = f2bf(p0);
        ((unsigned short*)&pa1[ks])[jj] = f2bf(p1);
      }
    }
    sum0 += __shfl_xor(sum0, 32);
    sum1 += __shfl_xor(sum1, 32);
    if (hh == 0) {
      SIp[wave * 48 + row0] = 1.f / sum0;
      if (r1ok) SIp[wave * 48 + row1] = 1.f / sum1;
    }

    const unsigned short* Gt = (const unsigned short*)(smem + G1T_OFF);
#pragma unroll
    for (int ks = 0; ks < 3; ++ks) {
      bf16x8 bfrag = *(const bf16x8*)(Gt + wave * 1792 + l32 * 56 + ks * 16 + hh * 8);
      pv0 = __builtin_amdgcn_mfma_f32_32x32x16_bf16(pa0[ks], bfrag, pv0, 0, 0, 0);
      pv1 = __builtin_amdgcn_mfma_f32_32x32x16_bf16(pa1[ks], bfrag, pv1, 0, 0, 0);
    }
  }
  __syncthreads();   // g1T reads done before H1 aliases

  // ===== PV epilogue: scale by 1/sum, ELU, -> H1[48][264] bf16; zero pad rows =====
  {
    unsigned short* H1p = (unsigned short*)(smem + H1_OFF);
    const float* SIp = (const float*)(smem + SI_OFF);
#pragma unroll
    for (int mt = 0; mt < 2; ++mt)
#pragma unroll
      for (int rg = 0; rg < 16; ++rg) {
        int row = mt * 32 + (rg & 3) + 8 * (rg >> 2) + 4 * hh;  // 32x32 C layout
        if (row < NN) {
          float v = (mt ? pv1[rg] : pv0[rg]) * SIp[wave * 48 + row];
          v = v > 0.f ? v : __expf(v) - 1.f;   // ELU
          H1p[row * 264 + wave * 32 + l32] = f2bf(v);
        }
      }
    if (tid < 132) *(unsigned long long*)((char*)H1p + 46 * 528 + tid * 8) = 0ull;
  }
  __syncthreads();

  // ===== Phase 4: g2 = h1 @ W2 (46x64, K=256), B frags from L2-resident W2T =====
  {
    const unsigned short* H1p = (const unsigned short*)(smem + H1_OFF);
    float* G2p = (float*)(smem + G2_OFF);
    for (int tile = wave; tile < 12; tile += 8) {
      int rt = tile >> 2, ct = tile & 3;
      f32x4 a4 = 0;
#pragma unroll
      for (int ks = 0; ks < 8; ++ks) {
        bf16x8 af = *(const bf16x8*)(H1p + (rt * 16 + l16) * 264 + ks * 32 + kq8);
        bf16x8 bw = *(const bf16x8*)(W2T + (ct * 16 + l16) * 256 + ks * 32 + kq8);
        a4 = __builtin_amdgcn_mfma_f32_16x16x32_bf16(af, bw, a4, 0, 0, 0);
      }
#pragma unroll
      for (int r = 0; r < 4; ++r) {
        int row = rt * 16 + rq4 + r;
        if (row < NN) G2p[row * 69 + ct * 16 + l16] = a4[r];
      }
    }
  }
  __syncthreads();

  // ===== Phase 5: s2_src/s2_dst/gmean per node (368 lanes, 8-lane reduce) =====
  {
    const float* G2p = (const float*)(smem + G2_OFF);
    float* S2S = (float*)(smem + S2S_OFF);
    float* S2D = (float*)(smem + S2D_OFF);
    float* GM  = (float*)(smem + GM_OFF);
    if (tid < NN * 8) {
      int n = tid >> 3, dp = (tid & 7) * 8;
      const float* g = G2p + n * 69 + dp;
      float ss = 0.f, sd = 0.f, gm = 0.f;
#pragma unroll
      for (int d = 0; d < 8; ++d) {
        float gv = g[d];
        ss += gv * a2[dp + d]; sd += gv * a2[64 + dp + d]; gm += gv;
      }
#pragma unroll
      for (int m = 1; m < 8; m <<= 1) {
        ss += __shfl_xor(ss, m); sd += __shfl_xor(sd, m); gm += __shfl_xor(gm, m);
      }
      if ((tid & 7) == 0) { S2S[n] = ss; S2D[n] = sd; GM[n] = gm * (1.f / 64.f); }
    }
  }
  __syncthreads();

  // ===== Phase 6: attn2 softmax + pooled[i] = sum_j p_ij * gmean[j] =====
  {
    const float* S2S = (const float*)(smem + S2S_OFF);
    const float* S2D = (const float*)(smem + S2D_OFF);
    const float* GM  = (const float*)(smem + GM_OFF);
    float* PL = (float*)(smem + PL_OFF);
    if (tid < NN) {
      float si = S2S[tid];
      float m = -1e30f;
      for (int j = 0; j < NN; ++j) m = fmaxf(m, lrelu(si + S2D[j]));
      float sum = 0.f, accp = 0.f;
      for (int j = 0; j < NN; ++j) {
        float p = __expf(lrelu(si + S2D[j]) - m);
        sum += p; accp += p * GM[j];
      }
      PL[tid] = accp / sum;
    }
  }
  __syncthreads();

  // ===== Phase 7: MLP head + sigmoid =====
  {
    const float* PL = (const float*)(smem + PL_OFF);
    float* Z1 = (float*)(smem + Z1_OFF);
    if (tid < 12) {
      float z = 0.f;
      for (int i = 0; i < NN; ++i) z += PL[i] * Wm1[i * 12 + tid];
      Z1[tid] = z + bm1[tid];
    }
    __syncthreads();
    if (tid == 0) {
      float z = 0.f;
#pragma unroll
      for (int mm = 0; mm < 12; ++mm) z += Z1[mm] * Wm2[mm];
      z += bm2[0];
      out[blockIdx.x] = 1.f / (1.f + __expf(-z));
    }
  }
}

// Transpose + bf16-cast weights once per launch into workspace.
__global__ void gat_prep(const float* __restrict__ W1, const float* __restrict__ W2,
                         unsigned short* __restrict__ W1T, unsigned short* __restrict__ W2T)
{
  int id = blockIdx.x * 256 + threadIdx.x;
  if (id < FIN * C1) {                 // W1 [1024][256] -> W1T [256][1024]
    int k = id >> 8, n = id & 255;
    W1T[n * FIN + k] = f2bf(W1[id]);
  }
  if (id < C1 * C2) {                  // W2 [256][64] -> W2T [64][256]
    int k = id >> 6, n = id & 63;
    W2T[n * C1 + k] = f2bf(W2[id]);
  }
}

extern "C" void kernel_launch(void* const* d_in, const int* in_sizes, int n_in,
                              void* d_out, int out_size, void* d_ws, size_t ws_size,
                              hipStream_t stream)
{
  const float* x   = (const float*)d_in[0];
  // d_in[1] = adj_mat (all ones by construction) — attention is dense, ignored
  const float* W1  = (const float*)d_in[2];
  const float* a1  = (const float*)d_in[3];
  const float* W2  = (const float*)d_in[4];
  const float* a2  = (const float*)d_in[5];
  const float* Wm1 = (const float*)d_in[6];
  const float* bm1 = (const float*)d_in[7];
  const float* Wm2 = (const float*)d_in[8];
  const float* bm2 = (const float*)d_in[9];
  float* out = (float*)d_out;

  unsigned short* W1T = (unsigned short*)d_ws;
  unsigned short* W2T = (unsigned short*)((char*)d_ws + (size_t)FIN * C1 * 2);

  int B = in_sizes[0] / NNF;

  hipLaunchKernelGGL(gat_prep, dim3(1024), dim3(256), 0, stream, W1, W2, W1T, W2T);
  hipLaunchKernelGGL(gat_main, dim3(B), dim3(512), 0, stream,
                     x, a1, a2, Wm1, bm1, Wm2, bm2, W1T, W2T, out);
}